// Round 5
// baseline (176.154 us; speedup 1.0000x reference)
//
#include <hip/hip_runtime.h>

// Shapes: B=4, NH=8, DIM=32, WS=8, WA=64, H=W=128, PLANE=16384.
// qkv:(4,8,96,128,128)f32  ch:(4,256,128,128)f32  lsc:(8)  btab:(225,8)
// pw:(256,256)  pb:(256)  ridx:(64,64)i32  out:(4,256,128,128)f32
//
// ws: biasG f32 [8][64][64] @0 (128 KB); wbf bf16 [256][256] @128K (128 KB)

typedef __attribute__((ext_vector_type(8))) short short8v;
typedef __attribute__((ext_vector_type(4))) float f32x4;
typedef __attribute__((ext_vector_type(2))) unsigned int u32x2;

#define PLANE 16384
#define LOG100 4.6051701859880914f

static __device__ __forceinline__ unsigned short f2bf(float x) {
  union { float f; unsigned u; } v; v.f = x;
  unsigned r = v.u + 0x7fff + ((v.u >> 16) & 1);
  return (unsigned short)(r >> 16);
}
static __device__ __forceinline__ float bf2f(unsigned short b) {
  union { unsigned u; float f; } v; v.u = ((unsigned)b) << 16;
  return v.f;
}

__global__ __launch_bounds__(256) void prep_kernel(
    const float* __restrict__ btab, const int* __restrict__ ridx,
    const float* __restrict__ pw, float* __restrict__ biasG,
    unsigned int* __restrict__ wbf)
{
  const int blk = blockIdx.x, tid = threadIdx.x;
  if (blk < 128) {                      // biasG[h][q][k]
    int i = blk * 256 + tid;
    int h = i >> 12, qk = i & 4095;
    biasG[i] = btab[ridx[qk] * 8 + h];
  } else {                              // w -> bf16 packed pairs
    int i = (blk - 128) * 256 + tid;
    wbf[i] = (unsigned)f2bf(pw[2 * i]) | ((unsigned)f2bf(pw[2 * i + 1]) << 16);
  }
}

// block = window-pair: 512 blocks x 512 threads (8 waves).
// Per head-iteration: wave = (win = wv>>2, strip = wv&3).
// LDS 80KB: x_lds bf16 [128][256] swizzled @0 (64KB, chm [32][132] f32 aliased)
//           K-stage hi @64K (8KB), lo @72K (8KB): u16 [128 pairpos][32 d]
__global__ __launch_bounds__(512, 4) void fused_kernel(
    const float* __restrict__ qkv, const float* __restrict__ ch,
    const float* __restrict__ lsc, const float* __restrict__ biasG,
    const unsigned short* __restrict__ wbf, const float* __restrict__ pb,
    float* __restrict__ out)
{
  __shared__ __align__(16) char smem[81920];
  float* chm = (float*)smem;                               // [32][132] f32
  unsigned short* sKhi = (unsigned short*)(smem + 65536);  // [128][32] u16
  unsigned short* sKlo = (unsigned short*)(smem + 73728);  // [128][32] u16

  const int tid = threadIdx.x;
  int bid = blockIdx.x;
  bid = (bid & 7) * 64 + (bid >> 3);         // XCD swizzle (512 = 8*64)
  const int b   = bid >> 7;
  const int wy  = (bid >> 3) & 15;
  const int wxp = bid & 7;
  const int y0  = wy << 3, x0 = wxp << 4;

  const int wv = tid >> 6, lane = tid & 63;
  const int lg = lane >> 4, lr = lane & 15;
  const int win = wv >> 2, st = wv & 3;
  const int xw  = x0 + win * 8;

  // ---- phase 1: chm[c][pairpos] = mean over 8 helper layers (coalesced f4)
  {
    const float* cb = ch + ((size_t)(b * 256)) * PLANE;
#pragma unroll
    for (int t = 0; t < 2; ++t) {
      int idx = tid + t * 512;               // (c, row, xq): 32*8*4 = 1024
      int c = idx >> 5, row = (idx >> 2) & 7, xq = idx & 3;
      const float4* src = (const float4*)(cb + (size_t)c * PLANE
                                          + (y0 + row) * 128 + x0) + xq;
      float4 a = {0.f, 0.f, 0.f, 0.f};
#pragma unroll
      for (int l = 0; l < 8; ++l) {
        float4 tv = src[(size_t)(l * 32) * (PLANE / 4)];
        a.x += tv.x; a.y += tv.y; a.z += tv.z; a.w += tv.w;
      }
      a.x *= 0.125f; a.y *= 0.125f; a.z *= 0.125f; a.w *= 0.125f;
      *(float4*)(chm + 132 * c + 16 * row + 4 * xq) = a;
    }
  }
  __syncthreads();

  // ---- phase 2: per-wave chm values -> packed bf16 regs (16 VGPR)
  // cpk[dt][m][0..3]: bf16 pairs of chm[16dt+lr][pa..pa+3], [pb..pb+3]
  unsigned cpk[2][2][4];
#pragma unroll
  for (int dt = 0; dt < 2; ++dt) {
    const float* cm = chm + 132 * (16 * dt + lr);
#pragma unroll
    for (int m = 0; m < 2; ++m) {
      int ka = 4 * lg + 32 * m, kb = ka + 16;
      int pa = 16 * (ka >> 3) + 8 * win + (ka & 7);
      int pb2 = 16 * (kb >> 3) + 8 * win + (kb & 7);
      f32x4 ca = *(const f32x4*)(cm + pa);
      f32x4 cb2 = *(const f32x4*)(cm + pb2);
      cpk[dt][m][0] = (unsigned)f2bf(ca[0]) | ((unsigned)f2bf(ca[1]) << 16);
      cpk[dt][m][1] = (unsigned)f2bf(ca[2]) | ((unsigned)f2bf(ca[3]) << 16);
      cpk[dt][m][2] = (unsigned)f2bf(cb2[0]) | ((unsigned)f2bf(cb2[1]) << 16);
      cpk[dt][m][3] = (unsigned)f2bf(cb2[2]) | ((unsigned)f2bf(cb2[3]) << 16);
    }
  }
  __syncthreads();   // chm region free -> x_lds

  // ---- K-stage thread mapping (coalesced loads, transpose-split writes)
  const int sq4 = tid & 3;                       // col-quad
  const int sdd = ((tid >> 2) & 15) | ((tid >> 8) << 4);  // d 0..31
  const int sr2 = (tid >> 6) & 3;                // rows sr2 and sr2+4
  const int sgo1 = (y0 + sr2) * 128 + x0 + 4 * sq4;
  const int sgo2 = (y0 + sr2 + 4) * 128 + x0 + 4 * sq4;
  const int sp1 = 16 * sr2 + 4 * sq4;
  const int sp2 = 16 * (sr2 + 4) + 4 * sq4;

  const size_t qkv0 = ((size_t)(b * 8) * 96) * PLANE;
  const float* kg0 = qkv + qkv0 + (size_t)(32 + sdd) * PLANE;

  float4 f1 = *(const float4*)(kg0 + sgo1);
  float4 f2 = *(const float4*)(kg0 + sgo2);

#pragma unroll 1
  for (int h = 0; h < 8; ++h) {
    // ---- stage K(h): split hi/lo, transposed b16 writes
    {
#define STG(val, pos_) { unsigned short hb_ = f2bf(val);                     \
        sKhi[32 * (pos_) + sdd] = hb_;                                       \
        sKlo[32 * (pos_) + sdd] = f2bf((val) - bf2f(hb_)); }
      STG(f1.x, sp1 + 0) STG(f1.y, sp1 + 1) STG(f1.z, sp1 + 2) STG(f1.w, sp1 + 3)
      STG(f2.x, sp2 + 0) STG(f2.y, sp2 + 1) STG(f2.z, sp2 + 2) STG(f2.w, sp2 + 3)
#undef STG
    }
    __syncthreads();

    // prefetch next head's K (hides under consume)
    if (h < 7) {
      const float* kgn = qkv + qkv0 + (size_t)((h + 1) * 96 + 32 + sdd) * PLANE;
      f1 = *(const float4*)(kgn + sgo1);
      f2 = *(const float4*)(kgn + sgo2);
    }

    // ---- consume: one strip per wave
    const float* qg = qkv + qkv0 + (size_t)(h * 96) * PLANE;
    const float* vg = qg + (size_t)64 * PLANE;
    const float scale = __expf(fminf(lsc[h], LOG100));
    const int q = 16 * st + lr;
    const int spq = (y0 + (q >> 3)) * 128 + xw + (q & 7);

    // issue Q loads early
    float qq[8];
#pragma unroll
    for (int j = 0; j < 8; ++j)
      qq[j] = qg[(size_t)(8 * lg + j) * PLANE + spq];

    // V*chm frags (own win), sigma-permuted
    short8v vf[2][2];
#pragma unroll
    for (int dt = 0; dt < 2; ++dt) {
      const float* vp = vg + (size_t)(16 * dt + lr) * PLANE;
#pragma unroll
      for (int m = 0; m < 2; ++m) {
        int ka = 4 * lg + 32 * m, kb = ka + 16;
        float4 va = *(const float4*)(vp + (y0 + (ka >> 3)) * 128 + xw + (ka & 7));
        float4 vb = *(const float4*)(vp + (y0 + (kb >> 3)) * 128 + xw + (kb & 7));
        const unsigned* cp = cpk[dt][m];
        vf[dt][m][0] = (short)f2bf(va.x * bf2f((unsigned short)(cp[0] & 0xffff)));
        vf[dt][m][1] = (short)f2bf(va.y * bf2f((unsigned short)(cp[0] >> 16)));
        vf[dt][m][2] = (short)f2bf(va.z * bf2f((unsigned short)(cp[1] & 0xffff)));
        vf[dt][m][3] = (short)f2bf(va.w * bf2f((unsigned short)(cp[1] >> 16)));
        vf[dt][m][4] = (short)f2bf(vb.x * bf2f((unsigned short)(cp[2] & 0xffff)));
        vf[dt][m][5] = (short)f2bf(vb.y * bf2f((unsigned short)(cp[2] >> 16)));
        vf[dt][m][6] = (short)f2bf(vb.z * bf2f((unsigned short)(cp[3] & 0xffff)));
        vf[dt][m][7] = (short)f2bf(vb.w * bf2f((unsigned short)(cp[3] >> 16)));
      }
    }

    // K frags from stage (pre-split) + k-norms from hi+lo reconstruction
    short8v khi[4], klo[4];
    float ivk[4];
#pragma unroll
    for (int kt = 0; kt < 4; ++kt) {
      int pp = 16 * (2 * kt + (lr >> 3)) + 8 * win + (lr & 7);
      khi[kt] = *(const short8v*)(sKhi + 32 * pp + 8 * lg);
      klo[kt] = *(const short8v*)(sKlo + 32 * pp + 8 * lg);
      float nr = 0.f;
#pragma unroll
      for (int j = 0; j < 8; ++j) {
        float kr = bf2f((unsigned short)khi[kt][j]) + bf2f((unsigned short)klo[kt][j]);
        nr = fmaf(kr, kr, nr);
      }
      nr += __shfl_xor(nr, 16);
      nr += __shfl_xor(nr, 32);
      ivk[kt] = 1.f / fmaxf(sqrtf(nr), 1e-12f);
    }

    // Q norm + raw hi/lo split (scale applied post-MFMA)
    float nrq = 0.f;
#pragma unroll
    for (int j = 0; j < 8; ++j) nrq = fmaf(qq[j], qq[j], nrq);
    nrq += __shfl_xor(nrq, 16);
    nrq += __shfl_xor(nrq, 32);
    const float fq = scale / fmaxf(sqrtf(nrq), 1e-12f);

    short8v qhi, qlo;
#pragma unroll
    for (int j = 0; j < 8; ++j) {
      unsigned short hb = f2bf(qq[j]);
      qhi[j] = (short)hb;
      qlo[j] = (short)f2bf(qq[j] - bf2f(hb));
    }

    // S^T tiles + logits + lane-local softmax (kpos = 16kt + 4lg + r)
    const float4* bq = (const float4*)(biasG + (h << 12) + (q << 6));
    float e[16], mx = -1e30f;
#pragma unroll
    for (int kt = 0; kt < 4; ++kt) {
      f32x4 a = {0.f, 0.f, 0.f, 0.f};
      a = __builtin_amdgcn_mfma_f32_16x16x32_bf16(klo[kt], qhi, a, 0, 0, 0);
      a = __builtin_amdgcn_mfma_f32_16x16x32_bf16(khi[kt], qlo, a, 0, 0, 0);
      a = __builtin_amdgcn_mfma_f32_16x16x32_bf16(khi[kt], qhi, a, 0, 0, 0);
      float4 b4 = bq[4 * kt + lg];
      float bb[4] = {b4.x, b4.y, b4.z, b4.w};
#pragma unroll
      for (int r = 0; r < 4; ++r) {
        float fkr = __shfl(ivk[kt], 4 * lg + r);
        float lv = a[r] * (fq * fkr) + bb[r];
        e[4 * kt + r] = lv;
        mx = fmaxf(mx, lv);
      }
    }
    mx = fmaxf(mx, __shfl_xor(mx, 16));
    mx = fmaxf(mx, __shfl_xor(mx, 32));
    float s = 0.f;
#pragma unroll
    for (int i = 0; i < 16; ++i) { e[i] = __expf(e[i] - mx); s += e[i]; }
    s += __shfl_xor(s, 16);
    s += __shfl_xor(s, 32);
    float rl = 1.f / s;

    // P B-frags, sigma-permuted
    short8v pf[2];
#pragma unroll
    for (int m = 0; m < 2; ++m)
#pragma unroll
      for (int j = 0; j < 8; ++j)
        pf[m][j] = (short)f2bf(e[4 * (j >> 2) + 8 * m + (j & 3)]);

    // PV; store to swizzled x_lds: byte = pl*512 + (2c ^ ((pl&7)<<4))
    int pl = ((q >> 3) << 4) + win * 8 + (q & 7);
#pragma unroll
    for (int dt = 0; dt < 2; ++dt) {
      f32x4 o = {0.f, 0.f, 0.f, 0.f};
      o = __builtin_amdgcn_mfma_f32_16x16x32_bf16(vf[dt][0], pf[0], o, 0, 0, 0);
      o = __builtin_amdgcn_mfma_f32_16x16x32_bf16(vf[dt][1], pf[1], o, 0, 0, 0);
      u32x2 ww;
      ww[0] = (unsigned)f2bf(o[0] * rl) | ((unsigned)f2bf(o[1] * rl) << 16);
      ww[1] = (unsigned)f2bf(o[2] * rl) | ((unsigned)f2bf(o[3] * rl) << 16);
      unsigned off = (unsigned)(pl * 512)
                   + (((unsigned)(64 * h + 32 * dt + 8 * lg)) ^ ((unsigned)(pl & 7) << 4));
      *(u32x2*)(smem + off) = ww;
    }
    __syncthreads();
  }

  // ---- projection: wave wv computes o in [32wv, 32wv+32) x 128 positions
  f32x4 acc[2][8];
#pragma unroll
  for (int i = 0; i < 2; ++i)
#pragma unroll
    for (int j = 0; j < 8; ++j) acc[i][j] = (f32x4){0.f, 0.f, 0.f, 0.f};

#pragma unroll 1
  for (int kc = 0; kc < 8; ++kc) {
    short8v wf0 = *(const short8v*)(wbf + (size_t)(32 * wv + lr) * 256 + 32 * kc + 8 * lg);
    short8v wf1 = *(const short8v*)(wbf + (size_t)(32 * wv + 16 + lr) * 256 + 32 * kc + 8 * lg);
    short8v xf[8];
#pragma unroll
    for (int pt = 0; pt < 8; ++pt) {
      int pl = 16 * pt + lr;
      unsigned off = (unsigned)(pl * 512)
                   + (((unsigned)(64 * kc + 16 * lg)) ^ ((unsigned)(pl & 7) << 4));
      xf[pt] = *(const short8v*)(smem + off);
    }
#pragma unroll
    for (int pt = 0; pt < 8; ++pt) {
      acc[0][pt] = __builtin_amdgcn_mfma_f32_16x16x32_bf16(wf0, xf[pt], acc[0][pt], 0, 0, 0);
      acc[1][pt] = __builtin_amdgcn_mfma_f32_16x16x32_bf16(wf1, xf[pt], acc[1][pt], 0, 0, 0);
    }
  }

#pragma unroll
  for (int ot = 0; ot < 2; ++ot) {
#pragma unroll
    for (int r = 0; r < 4; ++r) {
      int o = 32 * wv + 16 * ot + 4 * lg + r;
      float bv = pb[o];
      float* op = out + ((size_t)(b * 256 + o)) * PLANE;
#pragma unroll
      for (int pt = 0; pt < 8; ++pt)
        op[(y0 + pt) * 128 + x0 + lr] = acc[ot][pt][r] + bv;
    }
  }
}

extern "C" void kernel_launch(void* const* d_in, const int* in_sizes, int n_in,
                              void* d_out, int out_size, void* d_ws, size_t ws_size,
                              hipStream_t stream) {
  const float* qkv  = (const float*)d_in[0];
  const float* ch   = (const float*)d_in[1];
  const float* lsc  = (const float*)d_in[2];
  const float* btab = (const float*)d_in[3];
  const float* pw   = (const float*)d_in[4];
  const float* pb   = (const float*)d_in[5];
  const int*   ridx = (const int*)d_in[6];
  float* out = (float*)d_out;

  char* ws = (char*)d_ws;
  float*          biasG = (float*)ws;                      // 128 KB
  unsigned short* wbf   = (unsigned short*)(ws + 131072);  // 128 KB

  prep_kernel<<<dim3(256), dim3(256), 0, stream>>>(btab, ridx, pw,
                                                   biasG, (unsigned int*)wbf);
  fused_kernel<<<dim3(512), dim3(512), 0, stream>>>(qkv, ch, lsc, biasG,
                                                    wbf, pb, out);
}